// Round 4
// baseline (840.195 us; speedup 1.0000x reference)
//
#include <hip/hip_runtime.h>
#include <hip/hip_bf16.h>

typedef __hip_bfloat16 bf16;
typedef short bf16x8v __attribute__((ext_vector_type(8)));
typedef float f32x4v __attribute__((ext_vector_type(4)));

union U8 { bf16 h[8]; bf16x8v v; };

#define MFMA(a, b, c) __builtin_amdgcn_mfma_f32_16x16x32_bf16((a), (b), (c), 0, 0, 0)

// ---------------------------------------------------------------------------
// K0: transpose + f32->bf16 convert the four 512x512 weight matrices into
// [n][k] layout so MFMA B-fragments are contiguous 16B reads. WT=[4][512][512].
// ---------------------------------------------------------------------------
__global__ __launch_bounds__(1024) void conv_weights(
    const float* __restrict__ Wq, const float* __restrict__ Wk,
    const float* __restrict__ Wv, const float* __restrict__ Wp,
    bf16* __restrict__ WT) {
  __shared__ float t[32][33];
  const float* srcs[4] = {Wq, Wk, Wv, Wp};
  const float* src = srcs[blockIdx.z];
  int k0 = blockIdx.y * 32, n0 = blockIdx.x * 32;
  t[threadIdx.y][threadIdx.x] = src[(size_t)(k0 + threadIdx.y) * 512 + n0 + threadIdx.x];
  __syncthreads();
  WT[((size_t)blockIdx.z * 512 + n0 + threadIdx.y) * 512 + k0 + threadIdx.x] =
      (bf16)t[threadIdx.x][threadIdx.y];
}

// ---------------------------------------------------------------------------
// K0b: convert X (8*2048*512 f32) to canonical bf16 (parked in the Y region
// of d_out; consumed by qkv_gemm before proj_ln overwrites Y).
// ---------------------------------------------------------------------------
__global__ __launch_bounds__(256) void conv_x(const float* __restrict__ x,
                                              bf16* __restrict__ Xb) {
  size_t base = ((size_t)blockIdx.x * 256 + threadIdx.x) * 8;
  f32x4v a = *(const f32x4v*)(x + base);
  f32x4v b = *(const f32x4v*)(x + base + 4);
  U8 u;
#pragma unroll
  for (int e = 0; e < 4; e++) {
    u.h[e] = (bf16)a[e];
    u.h[4 + e] = (bf16)b[e];
  }
  *(bf16x8v*)(Xb + base) = u.v;
}

// ---------------------------------------------------------------------------
// K1: QKV projection GEMM. OUT[m][n] = sum_k Xb[m][k]*WT[n][k] + bias[n].
// 128x128 tile, BK=32, 256 threads (4 waves, 2x2 of 64x64).
// blockIdx.z selects Q / K / V. V is written transposed: Vt[b][h][s].
// ---------------------------------------------------------------------------
__global__ __launch_bounds__(256) void qkv_gemm(
    const bf16* __restrict__ Xb, const bf16* __restrict__ WTall,
    const float* __restrict__ bq, const float* __restrict__ bk,
    const float* __restrict__ bv,
    bf16* __restrict__ Q, bf16* __restrict__ Km, bf16* __restrict__ Vt) {
  const int which = blockIdx.z;
  const bf16* Wt = WTall + (size_t)which * 512 * 512;
  const float* bias = (which == 0) ? bq : (which == 1 ? bk : bv);
  const int n0 = blockIdx.x * 128;
  const int m0 = blockIdx.y * 128;
  __shared__ bf16 As[128][40];  // +8 pad -> 2-way LDS access (free)
  __shared__ bf16 Bs[128][40];
  const int tid = threadIdx.x;
  const int lane = tid & 63, w = tid >> 6;
  const int wr = w >> 1, wc = w & 1;
  const int quad = lane >> 4, l15 = lane & 15;

  f32x4v acc[4][4];
#pragma unroll
  for (int i = 0; i < 4; i++)
#pragma unroll
    for (int j = 0; j < 4; j++) acc[i][j] = (f32x4v){0.f, 0.f, 0.f, 0.f};

  const int srow = tid >> 2, scol = (tid & 3) * 8;
  for (int kt = 0; kt < 16; ++kt) {
    const int k0 = kt * 32;
#pragma unroll
    for (int it = 0; it < 2; ++it) {
      int r = srow + it * 64;
      *(bf16x8v*)&As[r][scol] = *(const bf16x8v*)&Xb[(size_t)(m0 + r) * 512 + k0 + scol];
      *(bf16x8v*)&Bs[r][scol] = *(const bf16x8v*)&Wt[(size_t)(n0 + r) * 512 + k0 + scol];
    }
    __syncthreads();
    bf16x8v a[4], b[4];
#pragma unroll
    for (int i = 0; i < 4; i++) a[i] = *(const bf16x8v*)&As[wr * 64 + i * 16 + l15][quad * 8];
#pragma unroll
    for (int j = 0; j < 4; j++) b[j] = *(const bf16x8v*)&Bs[wc * 64 + j * 16 + l15][quad * 8];
#pragma unroll
    for (int i = 0; i < 4; i++)
#pragma unroll
      for (int j = 0; j < 4; j++) acc[i][j] = MFMA(a[i], b[j], acc[i][j]);
    __syncthreads();
  }

#pragma unroll
  for (int j = 0; j < 4; j++) {
    int col = n0 + wc * 64 + j * 16 + l15;
    float bv_ = bias[col];
#pragma unroll
    for (int i = 0; i < 4; i++) {
#pragma unroll
      for (int r = 0; r < 4; r++) {
        int row = m0 + wr * 64 + i * 16 + quad * 4 + r;
        float v = acc[i][j][r] + bv_;
        if (which == 0) {
          Q[(size_t)row * 512 + col] = (bf16)v;
        } else if (which == 1) {
          Km[(size_t)row * 512 + col] = (bf16)v;
        } else {
          int b_ = row >> 11, s = row & 2047;
          Vt[((size_t)b_ * 512 + col) * 2048 + s] = (bf16)v;
        }
      }
    }
  }
}

// ---------------------------------------------------------------------------
// K2: fused attention. One block = one (batch, 16-row Q-tile).
// Phase 1: S = Q Kᵀ / sqrt(H), full 16x2048 row block in registers
//          (wave w covers seq cols [w*512, w*512+512), 128 f32 acc/lane).
// Phase 2: softmax (quad shuffles + cross-wave LDS reduce), then attn (f32)
//          written DIRECTLY from normalized registers.
// Phase 3: two 1024-col halves: P -> LDS (A-layout transform) -> O = P V.
// O is written IN PLACE over this block's own Q rows (row-disjoint, safe).
// ---------------------------------------------------------------------------
__global__ __launch_bounds__(256) void attn_kernel(
    const bf16* __restrict__ Q, const bf16* __restrict__ Km,
    const bf16* __restrict__ Vt, float* __restrict__ attn,
    bf16* __restrict__ O) {
  __shared__ __align__(16) bf16 Ps[16][1032];  // 33,024 B (phase 3 staging)
  __shared__ float red[128];
  bf16 (*Qs)[520] = (bf16(*)[520])&Ps[0][0];   // first 16,640 B alias (phase 1)

  const int tileid = blockIdx.x;
  const int b = tileid >> 7;
  const int q0 = (tileid & 127) << 4;
  const int tid = threadIdx.x, lane = tid & 63, w = tid >> 6;
  const int quad = lane >> 4, l15 = lane & 15;
  const float scale = 0.044194173824159216f;  // 1/sqrt(512)

  // stage Q tile -> LDS
#pragma unroll
  for (int it = 0; it < 4; ++it) {
    int e = it * 256 + tid;
    int row = e >> 6, c8 = (e & 63) * 8;
    *(bf16x8v*)&Qs[row][c8] =
        *(const bf16x8v*)&Q[((size_t)(b * 2048) + q0 + row) * 512 + c8];
  }
  __syncthreads();

  bf16x8v a[16];
#pragma unroll
  for (int kk = 0; kk < 16; kk++) a[kk] = *(const bf16x8v*)&Qs[l15][kk * 32 + quad * 8];

  f32x4v acc[32];
#pragma unroll
  for (int c = 0; c < 32; c++) acc[c] = (f32x4v){0.f, 0.f, 0.f, 0.f};

  const bf16* Kb = Km + (size_t)b * 2048 * 512;
#pragma unroll
  for (int c = 0; c < 32; c++) {
    int s = w * 512 + c * 16 + l15;
    const bf16* kr = Kb + (size_t)s * 512 + quad * 8;
#pragma unroll
    for (int kk = 0; kk < 16; kk++) {
      bf16x8v bfr = *(const bf16x8v*)(kr + kk * 32);
      acc[c] = MFMA(a[kk], bfr, acc[c]);
    }
  }
#pragma unroll
  for (int c = 0; c < 32; c++) acc[c] = acc[c] * scale;

  // --- softmax stats ---
  float m[4], l[4];
#pragma unroll
  for (int r = 0; r < 4; r++) m[r] = -1e30f;
#pragma unroll
  for (int c = 0; c < 32; c++)
#pragma unroll
    for (int r = 0; r < 4; r++) m[r] = fmaxf(m[r], acc[c][r]);
#pragma unroll
  for (int off = 1; off < 16; off <<= 1)
#pragma unroll
    for (int r = 0; r < 4; r++) m[r] = fmaxf(m[r], __shfl_xor(m[r], off, 64));
  if (l15 == 0)
#pragma unroll
    for (int r = 0; r < 4; r++) red[w * 16 + quad * 4 + r] = m[r];
  __syncthreads();
#pragma unroll
  for (int r = 0; r < 4; r++) {
    int row = quad * 4 + r;
    float mm = red[row];
    for (int ww = 1; ww < 4; ww++) mm = fmaxf(mm, red[ww * 16 + row]);
    m[r] = mm;
  }
#pragma unroll
  for (int r = 0; r < 4; r++) l[r] = 0.f;
#pragma unroll
  for (int c = 0; c < 32; c++)
#pragma unroll
    for (int r = 0; r < 4; r++) {
      float p = __expf(acc[c][r] - m[r]);
      acc[c][r] = p;
      l[r] += p;
    }
#pragma unroll
  for (int off = 1; off < 16; off <<= 1)
#pragma unroll
    for (int r = 0; r < 4; r++) l[r] += __shfl_xor(l[r], off, 64);
  if (l15 == 0)
#pragma unroll
    for (int r = 0; r < 4; r++) red[64 + w * 16 + quad * 4 + r] = l[r];
  __syncthreads();
#pragma unroll
  for (int r = 0; r < 4; r++) {
    int row = quad * 4 + r;
    float s_ = 0.f;
    for (int ww = 0; ww < 4; ww++) s_ += red[64 + ww * 16 + row];
    l[r] = 1.0f / s_;
  }

  // normalize in registers and write attn (f32) directly
#pragma unroll
  for (int c = 0; c < 32; c++) {
#pragma unroll
    for (int r = 0; r < 4; r++) {
      float p = acc[c][r] * l[r];
      acc[c][r] = p;
      attn[((size_t)(b * 2048) + q0 + quad * 4 + r) * 2048 + w * 512 + c * 16 + l15] = p;
    }
  }

  // --- two halves: P->LDS (bf16, A-layout), O accumulation ---
  f32x4v acc2[8];
#pragma unroll
  for (int j = 0; j < 8; j++) acc2[j] = (f32x4v){0.f, 0.f, 0.f, 0.f};
  const bf16* Vb = Vt + (size_t)b * 512 * 2048;

  for (int h = 0; h < 2; ++h) {
    __syncthreads();  // prior-half LDS reads (and Qs reads) complete
    if ((w >> 1) == h) {
      int cbase = (w & 1) * 512;
#pragma unroll
      for (int c = 0; c < 32; c++) {
        int colL = cbase + c * 16 + l15;
#pragma unroll
        for (int r = 0; r < 4; r++) Ps[quad * 4 + r][colL] = (bf16)acc[c][r];
      }
    }
    __syncthreads();
    // O += P_half @ V_half : wave w -> hidden cols [w*128, w*128+128)
    for (int kk = 0; kk < 32; ++kk) {
      bf16x8v ap = *(const bf16x8v*)&Ps[l15][kk * 32 + quad * 8];
#pragma unroll
      for (int j = 0; j < 8; j++) {
        int n = w * 128 + j * 16 + l15;
        bf16x8v bv8 =
            *(const bf16x8v*)&Vb[(size_t)n * 2048 + h * 1024 + kk * 32 + quad * 8];
        acc2[j] = MFMA(ap, bv8, acc2[j]);
      }
    }
  }

#pragma unroll
  for (int j = 0; j < 8; j++) {
    int col = w * 128 + j * 16 + l15;
#pragma unroll
    for (int r = 0; r < 4; r++) {
      int row = q0 + quad * 4 + r;
      O[((size_t)b * 2048 + row) * 512 + col] = (bf16)acc2[j][r];
    }
  }
}

// ---------------------------------------------------------------------------
// K3: out-projection + bias + residual + LayerNorm, fused. Output f32.
// BM=64 rows/block (16/wave), BN=512 (full row per wave -> LN reduction is
// in-lane + shuffles only).
// ---------------------------------------------------------------------------
__global__ __launch_bounds__(256) void proj_ln(
    const bf16* __restrict__ O, const bf16* __restrict__ WTp,
    const float* __restrict__ bp, const float* __restrict__ X,
    const float* __restrict__ gamma, const float* __restrict__ beta,
    float* __restrict__ Y) {
  __shared__ bf16 Bs[512][40];
  const int m0 = blockIdx.x * 64;
  const int tid = threadIdx.x, lane = tid & 63, w = tid >> 6;
  const int quad = lane >> 4, l15 = lane & 15;

  f32x4v acc[32];
#pragma unroll
  for (int j = 0; j < 32; j++) acc[j] = (f32x4v){0.f, 0.f, 0.f, 0.f};

  const int srow = tid >> 2, scol = (tid & 3) * 8;
  for (int kt = 0; kt < 16; ++kt) {
    const int k0 = kt * 32;
#pragma unroll
    for (int it = 0; it < 8; ++it) {
      int r = it * 64 + srow;
      *(bf16x8v*)&Bs[r][scol] = *(const bf16x8v*)&WTp[(size_t)r * 512 + k0 + scol];
    }
    __syncthreads();
    bf16x8v a_ = *(const bf16x8v*)&O[(size_t)(m0 + w * 16 + l15) * 512 + k0 + quad * 8];
#pragma unroll
    for (int j = 0; j < 32; j++) {
      bf16x8v b_ = *(const bf16x8v*)&Bs[j * 16 + l15][quad * 8];
      acc[j] = MFMA(a_, b_, acc[j]);
    }
    __syncthreads();
  }

  // y = out + bp + x ; then LayerNorm per row
#pragma unroll
  for (int j = 0; j < 32; j++) {
    int col = j * 16 + l15;
    float bpv = bp[col];
#pragma unroll
    for (int r = 0; r < 4; r++) {
      size_t row = m0 + w * 16 + quad * 4 + r;
      acc[j][r] = acc[j][r] + bpv + X[row * 512 + col];
    }
  }
  float s1[4] = {0.f, 0.f, 0.f, 0.f}, s2[4] = {0.f, 0.f, 0.f, 0.f};
#pragma unroll
  for (int j = 0; j < 32; j++)
#pragma unroll
    for (int r = 0; r < 4; r++) {
      s1[r] += acc[j][r];
      s2[r] += acc[j][r] * acc[j][r];
    }
#pragma unroll
  for (int off = 1; off < 16; off <<= 1)
#pragma unroll
    for (int r = 0; r < 4; r++) {
      s1[r] += __shfl_xor(s1[r], off, 64);
      s2[r] += __shfl_xor(s2[r], off, 64);
    }
  float mu[4], rs[4];
#pragma unroll
  for (int r = 0; r < 4; r++) {
    mu[r] = s1[r] * (1.0f / 512.0f);
    float var = s2[r] * (1.0f / 512.0f) - mu[r] * mu[r];
    rs[r] = rsqrtf(var + 1e-5f);
  }
#pragma unroll
  for (int j = 0; j < 32; j++) {
    int col = j * 16 + l15;
    float g = gamma[col], be = beta[col];
#pragma unroll
    for (int r = 0; r < 4; r++) {
      int row = m0 + w * 16 + quad * 4 + r;
      Y[(size_t)row * 512 + col] = (acc[j][r] - mu[r]) * rs[r] * g + be;
    }
  }
}

// ---------------------------------------------------------------------------
extern "C" void kernel_launch(void* const* d_in, const int* in_sizes, int n_in,
                              void* d_out, int out_size, void* d_ws, size_t ws_size,
                              hipStream_t stream) {
  const float* x = (const float*)d_in[0];
  const float* Wq = (const float*)d_in[1];
  const float* bq = (const float*)d_in[2];
  const float* Wk = (const float*)d_in[3];
  const float* bk = (const float*)d_in[4];
  const float* Wv = (const float*)d_in[5];
  const float* bv = (const float*)d_in[6];
  const float* Wp = (const float*)d_in[7];
  const float* bp = (const float*)d_in[8];
  const float* gamma = (const float*)d_in[9];
  const float* beta = (const float*)d_in[10];

  char* ws = (char*)d_ws;
  bf16* WT = (bf16*)ws;                                      // 2 MB
  size_t off = 4ull * 512 * 512 * 2;
  bf16* Qd = (bf16*)(ws + off); off += 16384ull * 512 * 2;   // 16 MB
  bf16* Kd = (bf16*)(ws + off); off += 16384ull * 512 * 2;   // 16 MB
  bf16* Vtd = (bf16*)(ws + off); off += 16384ull * 512 * 2;  // 16 MB (total 50 MB)

  float* Y = (float*)d_out;                     // f32 [8][2048][512]
  float* attn = Y + 8ull * 2048 * 512;          // f32 [8][2048][2048]
  bf16* Xb = (bf16*)d_out;  // bf16 X parked in Y region (consumed by qkv_gemm)
  bf16* Od = Qd;            // O overwrites Q in place (row-disjoint per block)

  hipLaunchKernelGGL(conv_weights, dim3(16, 16, 4), dim3(32, 32), 0, stream,
                     Wq, Wk, Wv, Wp, WT);
  hipLaunchKernelGGL(conv_x, dim3(4096), dim3(256), 0, stream, x, Xb);
  hipLaunchKernelGGL(qkv_gemm, dim3(4, 128, 3), dim3(256), 0, stream,
                     Xb, WT, bq, bk, bv, Qd, Kd, Vtd);
  hipLaunchKernelGGL(attn_kernel, dim3(1024), dim3(256), 0, stream,
                     Qd, Kd, Vtd, attn, Od);
  hipLaunchKernelGGL(proj_ln, dim3(256), dim3(256), 0, stream,
                     Od, WT + 3ull * 512 * 512, bp, x, gamma, beta, Y);
}

// Round 5
// 719.179 us; speedup vs baseline: 1.1683x; 1.1683x over previous
//
#include <hip/hip_runtime.h>
#include <hip/hip_bf16.h>

typedef __hip_bfloat16 bf16;
typedef short bf16x8v __attribute__((ext_vector_type(8)));
typedef float f32x4v __attribute__((ext_vector_type(4)));

union U8 { bf16 h[8]; bf16x8v v; };

#define MFMA(a, b, c) __builtin_amdgcn_mfma_f32_16x16x32_bf16((a), (b), (c), 0, 0, 0)

// ---------------------------------------------------------------------------
// K0: transpose + f32->bf16 convert the four 512x512 weight matrices into
// [n][k] layout so MFMA B-fragments are contiguous 16B reads. WT=[4][512][512].
// ---------------------------------------------------------------------------
__global__ __launch_bounds__(1024) void conv_weights(
    const float* __restrict__ Wq, const float* __restrict__ Wk,
    const float* __restrict__ Wv, const float* __restrict__ Wp,
    bf16* __restrict__ WT) {
  __shared__ float t[32][33];
  const float* srcs[4] = {Wq, Wk, Wv, Wp};
  const float* src = srcs[blockIdx.z];
  int k0 = blockIdx.y * 32, n0 = blockIdx.x * 32;
  t[threadIdx.y][threadIdx.x] = src[(size_t)(k0 + threadIdx.y) * 512 + n0 + threadIdx.x];
  __syncthreads();
  WT[((size_t)blockIdx.z * 512 + n0 + threadIdx.y) * 512 + k0 + threadIdx.x] =
      (bf16)t[threadIdx.x][threadIdx.y];
}

// ---------------------------------------------------------------------------
// K0b: convert X (8*2048*512 f32) to canonical bf16 (parked in the Y region
// of d_out; consumed by qkv_gemm before proj_ln overwrites Y).
// ---------------------------------------------------------------------------
__global__ __launch_bounds__(256) void conv_x(const float* __restrict__ x,
                                              bf16* __restrict__ Xb) {
  size_t base = ((size_t)blockIdx.x * 256 + threadIdx.x) * 8;
  f32x4v a = *(const f32x4v*)(x + base);
  f32x4v b = *(const f32x4v*)(x + base + 4);
  U8 u;
#pragma unroll
  for (int e = 0; e < 4; e++) {
    u.h[e] = (bf16)a[e];
    u.h[4 + e] = (bf16)b[e];
  }
  *(bf16x8v*)(Xb + base) = u.v;
}

// ---------------------------------------------------------------------------
// K1: QKV projection GEMM. OUT[m][n] = sum_k Xb[m][k]*WT[n][k] + bias[n].
// 128x128 tile, BK=32, 256 threads (4 waves, 2x2 of 64x64).
// blockIdx.z selects Q / K / V. V is written transposed: Vt[b][h][s].
// ---------------------------------------------------------------------------
__global__ __launch_bounds__(256) void qkv_gemm(
    const bf16* __restrict__ Xb, const bf16* __restrict__ WTall,
    const float* __restrict__ bq, const float* __restrict__ bk,
    const float* __restrict__ bv,
    bf16* __restrict__ Q, bf16* __restrict__ Km, bf16* __restrict__ Vt) {
  const int which = blockIdx.z;
  const bf16* Wt = WTall + (size_t)which * 512 * 512;
  const float* bias = (which == 0) ? bq : (which == 1 ? bk : bv);
  const int n0 = blockIdx.x * 128;
  const int m0 = blockIdx.y * 128;
  __shared__ bf16 As[128][40];
  __shared__ bf16 Bs[128][40];
  const int tid = threadIdx.x;
  const int lane = tid & 63, w = tid >> 6;
  const int wr = w >> 1, wc = w & 1;
  const int quad = lane >> 4, l15 = lane & 15;

  f32x4v acc[4][4];
#pragma unroll
  for (int i = 0; i < 4; i++)
#pragma unroll
    for (int j = 0; j < 4; j++) acc[i][j] = (f32x4v){0.f, 0.f, 0.f, 0.f};

  const int srow = tid >> 2, scol = (tid & 3) * 8;
  for (int kt = 0; kt < 16; ++kt) {
    const int k0 = kt * 32;
#pragma unroll
    for (int it = 0; it < 2; ++it) {
      int r = srow + it * 64;
      *(bf16x8v*)&As[r][scol] = *(const bf16x8v*)&Xb[(size_t)(m0 + r) * 512 + k0 + scol];
      *(bf16x8v*)&Bs[r][scol] = *(const bf16x8v*)&Wt[(size_t)(n0 + r) * 512 + k0 + scol];
    }
    __syncthreads();
    bf16x8v a[4], b[4];
#pragma unroll
    for (int i = 0; i < 4; i++) a[i] = *(const bf16x8v*)&As[wr * 64 + i * 16 + l15][quad * 8];
#pragma unroll
    for (int j = 0; j < 4; j++) b[j] = *(const bf16x8v*)&Bs[wc * 64 + j * 16 + l15][quad * 8];
#pragma unroll
    for (int i = 0; i < 4; i++)
#pragma unroll
      for (int j = 0; j < 4; j++) acc[i][j] = MFMA(a[i], b[j], acc[i][j]);
    __syncthreads();
  }

#pragma unroll
  for (int j = 0; j < 4; j++) {
    int col = n0 + wc * 64 + j * 16 + l15;
    float bv_ = bias[col];
#pragma unroll
    for (int i = 0; i < 4; i++) {
#pragma unroll
      for (int r = 0; r < 4; r++) {
        int row = m0 + wr * 64 + i * 16 + quad * 4 + r;
        float v = acc[i][j][r] + bv_;
        if (which == 0) {
          Q[(size_t)row * 512 + col] = (bf16)v;
        } else if (which == 1) {
          Km[(size_t)row * 512 + col] = (bf16)v;
        } else {
          int b_ = row >> 11, s = row & 2047;
          Vt[((size_t)b_ * 512 + col) * 2048 + s] = (bf16)v;
        }
      }
    }
  }
}

// ---------------------------------------------------------------------------
// K2 v2: fused attention. One block = one (batch, 32-row Q-tile), 512 thr.
// Batch = blockIdx.x & 7  (XCD-aware: round-robin %8 block->XCD placement
// pins each batch's K/V (4 MB) to one XCD's 4 MB L2 -> no cross-batch thrash).
// Wave w: row-group rg=w>>2 (16 rows), col-group cg=w&3 (512 S-cols).
// Phase 1: S = Q K^T / sqrt(H) in registers (acc[32] f32x4 per lane).
// Phase 2: softmax (l15-shuffles + cross-wave LDS reduce), attn (f32) written
//          directly from normalized registers.
// Phase 3: 4 chunks of 512 S-cols: P chunk -> LDS (A-layout) -> O += P V.
//          Each V fragment feeds 2 MFMAs (both row-groups).
// O is written in place over this block's own Q rows (row-disjoint, safe).
// ---------------------------------------------------------------------------
__global__ __launch_bounds__(512) void attn_kernel(
    const bf16* __restrict__ Q, const bf16* __restrict__ Km,
    const bf16* __restrict__ Vt, float* __restrict__ attn,
    bf16* __restrict__ O) {
  __shared__ __align__(16) bf16 Ps[32][520];  // 33.3 KB: Qs (phase 1), P chunks (phase 3)
  __shared__ float red[512];

  const int b = blockIdx.x & 7;
  const int q0 = (blockIdx.x >> 3) << 5;
  const int tid = threadIdx.x, lane = tid & 63, w = tid >> 6;
  const int rg = w >> 2, cg = w & 3;
  const int quad = lane >> 4, l15 = lane & 15;
  const float scale = 0.044194173824159216f;  // 1/sqrt(512)

  // stage 32x512 Q tile -> LDS
#pragma unroll
  for (int it = 0; it < 4; ++it) {
    int e = it * 512 + tid;
    int row = e >> 6, c8 = (e & 63) * 8;
    *(bf16x8v*)&Ps[row][c8] =
        *(const bf16x8v*)&Q[((size_t)(b * 2048) + q0 + row) * 512 + c8];
  }
  __syncthreads();

  bf16x8v a[16];
#pragma unroll
  for (int kk = 0; kk < 16; kk++)
    a[kk] = *(const bf16x8v*)&Ps[rg * 16 + l15][kk * 32 + quad * 8];

  f32x4v acc[32];
#pragma unroll
  for (int c = 0; c < 32; c++) acc[c] = (f32x4v){0.f, 0.f, 0.f, 0.f};

  const bf16* Kb = Km + (size_t)b * 2048 * 512;
#pragma unroll
  for (int c = 0; c < 32; c++) {
    int s = cg * 512 + c * 16 + l15;
    const bf16* kr = Kb + (size_t)s * 512 + quad * 8;
#pragma unroll
    for (int kk = 0; kk < 16; kk++) {
      bf16x8v bfr = *(const bf16x8v*)(kr + kk * 32);
      acc[c] = MFMA(a[kk], bfr, acc[c]);
    }
  }
#pragma unroll
  for (int c = 0; c < 32; c++) acc[c] = acc[c] * scale;

  // --- softmax stats: reduce over cols (l15 lanes), then over 4 col-groups ---
  float m[4], l[4];
#pragma unroll
  for (int r = 0; r < 4; r++) m[r] = -1e30f;
#pragma unroll
  for (int c = 0; c < 32; c++)
#pragma unroll
    for (int r = 0; r < 4; r++) m[r] = fmaxf(m[r], acc[c][r]);
#pragma unroll
  for (int off = 1; off < 16; off <<= 1)
#pragma unroll
    for (int r = 0; r < 4; r++) m[r] = fmaxf(m[r], __shfl_xor(m[r], off, 64));
  if (l15 == 0)
#pragma unroll
    for (int r = 0; r < 4; r++) red[rg * 64 + cg * 16 + quad * 4 + r] = m[r];
  __syncthreads();
#pragma unroll
  for (int r = 0; r < 4; r++) {
    int row = rg * 64 + quad * 4 + r;
    float mm = red[row];
    for (int ww = 1; ww < 4; ww++) mm = fmaxf(mm, red[row + ww * 16]);
    m[r] = mm;
  }
#pragma unroll
  for (int r = 0; r < 4; r++) l[r] = 0.f;
#pragma unroll
  for (int c = 0; c < 32; c++)
#pragma unroll
    for (int r = 0; r < 4; r++) {
      float p = __expf(acc[c][r] - m[r]);
      acc[c][r] = p;
      l[r] += p;
    }
#pragma unroll
  for (int off = 1; off < 16; off <<= 1)
#pragma unroll
    for (int r = 0; r < 4; r++) l[r] += __shfl_xor(l[r], off, 64);
  if (l15 == 0)
#pragma unroll
    for (int r = 0; r < 4; r++) red[256 + rg * 64 + cg * 16 + quad * 4 + r] = l[r];
  __syncthreads();
#pragma unroll
  for (int r = 0; r < 4; r++) {
    int row = 256 + rg * 64 + quad * 4 + r;
    float s_ = 0.f;
    for (int ww = 0; ww < 4; ww++) s_ += red[row + ww * 16];
    l[r] = 1.0f / s_;
  }

  // normalize in registers and write attn (f32) directly
#pragma unroll
  for (int c = 0; c < 32; c++) {
#pragma unroll
    for (int r = 0; r < 4; r++) {
      float p = acc[c][r] * l[r];
      acc[c][r] = p;
      attn[((size_t)(b * 2048) + q0 + rg * 16 + quad * 4 + r) * 2048 + cg * 512 +
           c * 16 + l15] = p;
    }
  }

  // --- 4 chunks of 512 S-cols: P->LDS (bf16, A-layout), O accumulation ---
  f32x4v acc2[2][4];
#pragma unroll
  for (int hg = 0; hg < 2; hg++)
#pragma unroll
    for (int j = 0; j < 4; j++) acc2[hg][j] = (f32x4v){0.f, 0.f, 0.f, 0.f};
  const bf16* Vb = Vt + (size_t)b * 512 * 2048;

  for (int ch = 0; ch < 4; ++ch) {
    __syncthreads();  // prior chunk's Ps reads (and Qs reads) complete
    if (cg == ch) {
#pragma unroll
      for (int c = 0; c < 32; c++) {
        int colL = c * 16 + l15;
#pragma unroll
        for (int r = 0; r < 4; r++) Ps[rg * 16 + quad * 4 + r][colL] = (bf16)acc[c][r];
      }
    }
    __syncthreads();
    // O += P_chunk @ V_chunk : wave w -> hidden cols [w*64, w*64+64)
    for (int kk = 0; kk < 16; ++kk) {
      bf16x8v a0 = *(const bf16x8v*)&Ps[l15][kk * 32 + quad * 8];
      bf16x8v a1 = *(const bf16x8v*)&Ps[16 + l15][kk * 32 + quad * 8];
#pragma unroll
      for (int j = 0; j < 4; j++) {
        int n = w * 64 + j * 16 + l15;
        bf16x8v bv8 =
            *(const bf16x8v*)&Vb[(size_t)n * 2048 + ch * 512 + kk * 32 + quad * 8];
        acc2[0][j] = MFMA(a0, bv8, acc2[0][j]);
        acc2[1][j] = MFMA(a1, bv8, acc2[1][j]);
      }
    }
  }

#pragma unroll
  for (int hg = 0; hg < 2; hg++)
#pragma unroll
    for (int j = 0; j < 4; j++) {
      int col = w * 64 + j * 16 + l15;
#pragma unroll
      for (int r = 0; r < 4; r++) {
        int row = q0 + hg * 16 + quad * 4 + r;
        O[((size_t)b * 2048 + row) * 512 + col] = (bf16)acc2[hg][j][r];
      }
    }
}

// ---------------------------------------------------------------------------
// K3: out-projection + bias + residual + LayerNorm, fused. Output f32.
// BM=64 rows/block (16/wave), BN=512 (full row per wave -> LN reduction is
// in-lane + shuffles only).
// ---------------------------------------------------------------------------
__global__ __launch_bounds__(256) void proj_ln(
    const bf16* __restrict__ O, const bf16* __restrict__ WTp,
    const float* __restrict__ bp, const float* __restrict__ X,
    const float* __restrict__ gamma, const float* __restrict__ beta,
    float* __restrict__ Y) {
  __shared__ bf16 Bs[512][40];
  const int m0 = blockIdx.x * 64;
  const int tid = threadIdx.x, lane = tid & 63, w = tid >> 6;
  const int quad = lane >> 4, l15 = lane & 15;

  f32x4v acc[32];
#pragma unroll
  for (int j = 0; j < 32; j++) acc[j] = (f32x4v){0.f, 0.f, 0.f, 0.f};

  const int srow = tid >> 2, scol = (tid & 3) * 8;
  for (int kt = 0; kt < 16; ++kt) {
    const int k0 = kt * 32;
#pragma unroll
    for (int it = 0; it < 8; ++it) {
      int r = it * 64 + srow;
      *(bf16x8v*)&Bs[r][scol] = *(const bf16x8v*)&WTp[(size_t)r * 512 + k0 + scol];
    }
    __syncthreads();
    bf16x8v a_ = *(const bf16x8v*)&O[(size_t)(m0 + w * 16 + l15) * 512 + k0 + quad * 8];
#pragma unroll
    for (int j = 0; j < 32; j++) {
      bf16x8v b_ = *(const bf16x8v*)&Bs[j * 16 + l15][quad * 8];
      acc[j] = MFMA(a_, b_, acc[j]);
    }
    __syncthreads();
  }

#pragma unroll
  for (int j = 0; j < 32; j++) {
    int col = j * 16 + l15;
    float bpv = bp[col];
#pragma unroll
    for (int r = 0; r < 4; r++) {
      size_t row = m0 + w * 16 + quad * 4 + r;
      acc[j][r] = acc[j][r] + bpv + X[row * 512 + col];
    }
  }
  float s1[4] = {0.f, 0.f, 0.f, 0.f}, s2[4] = {0.f, 0.f, 0.f, 0.f};
#pragma unroll
  for (int j = 0; j < 32; j++)
#pragma unroll
    for (int r = 0; r < 4; r++) {
      s1[r] += acc[j][r];
      s2[r] += acc[j][r] * acc[j][r];
    }
#pragma unroll
  for (int off = 1; off < 16; off <<= 1)
#pragma unroll
    for (int r = 0; r < 4; r++) {
      s1[r] += __shfl_xor(s1[r], off, 64);
      s2[r] += __shfl_xor(s2[r], off, 64);
    }
  float mu[4], rs[4];
#pragma unroll
  for (int r = 0; r < 4; r++) {
    mu[r] = s1[r] * (1.0f / 512.0f);
    float var = s2[r] * (1.0f / 512.0f) - mu[r] * mu[r];
    rs[r] = rsqrtf(var + 1e-5f);
  }
#pragma unroll
  for (int j = 0; j < 32; j++) {
    int col = j * 16 + l15;
    float g = gamma[col], be = beta[col];
#pragma unroll
    for (int r = 0; r < 4; r++) {
      int row = m0 + w * 16 + quad * 4 + r;
      Y[(size_t)row * 512 + col] = (acc[j][r] - mu[r]) * rs[r] * g + be;
    }
  }
}

// ---------------------------------------------------------------------------
extern "C" void kernel_launch(void* const* d_in, const int* in_sizes, int n_in,
                              void* d_out, int out_size, void* d_ws, size_t ws_size,
                              hipStream_t stream) {
  const float* x = (const float*)d_in[0];
  const float* Wq = (const float*)d_in[1];
  const float* bq = (const float*)d_in[2];
  const float* Wk = (const float*)d_in[3];
  const float* bk = (const float*)d_in[4];
  const float* Wv = (const float*)d_in[5];
  const float* bv = (const float*)d_in[6];
  const float* Wp = (const float*)d_in[7];
  const float* bp = (const float*)d_in[8];
  const float* gamma = (const float*)d_in[9];
  const float* beta = (const float*)d_in[10];

  char* ws = (char*)d_ws;
  bf16* WT = (bf16*)ws;                                      // 2 MB
  size_t off = 4ull * 512 * 512 * 2;
  bf16* Qd = (bf16*)(ws + off); off += 16384ull * 512 * 2;   // 16 MB
  bf16* Kd = (bf16*)(ws + off); off += 16384ull * 512 * 2;   // 16 MB
  bf16* Vtd = (bf16*)(ws + off); off += 16384ull * 512 * 2;  // 16 MB (total 50 MB)

  float* Y = (float*)d_out;                     // f32 [8][2048][512]
  float* attn = Y + 8ull * 2048 * 512;          // f32 [8][2048][2048]
  bf16* Xb = (bf16*)d_out;  // bf16 X parked in Y region (consumed by qkv_gemm)
  bf16* Od = Qd;            // O overwrites Q in place (row-disjoint per block)

  hipLaunchKernelGGL(conv_weights, dim3(16, 16, 4), dim3(32, 32), 0, stream,
                     Wq, Wk, Wv, Wp, WT);
  hipLaunchKernelGGL(conv_x, dim3(4096), dim3(256), 0, stream, x, Xb);
  hipLaunchKernelGGL(qkv_gemm, dim3(4, 128, 3), dim3(256), 0, stream,
                     Xb, WT, bq, bk, bv, Qd, Kd, Vtd);
  hipLaunchKernelGGL(attn_kernel, dim3(512), dim3(512), 0, stream,
                     Qd, Kd, Vtd, attn, Od);
  hipLaunchKernelGGL(proj_ln, dim3(256), dim3(256), 0, stream,
                     Od, WT + 3ull * 512 * 512, bp, x, gamma, beta, Y);
}